// Round 2
// baseline (9151.053 us; speedup 1.0000x reference)
//
#include <hip/hip_runtime.h>
#include <hip/hip_bf16.h>
#include <stdint.h>

typedef __attribute__((ext_vector_type(8))) short bf16x8;
typedef __attribute__((ext_vector_type(4))) float f32x4;
typedef unsigned long long ull;

// ---- problem constants ----
#define N_SAMP 128
#define T_STEPS 512
#define RSLOTS 64

// ---- ws layout (bytes) ----
#define WT_OFF    0u           // bf16 weights, 3538944 B
#define GC_OFF    3538944u     // gconst fp32, 1179648 B
#define FLAG_OFF  4718592u     // flag[3][512][8] int, 49152 B
#define CONS_OFF  4767744u     // cons[3][512][8] int, 49152 B
#define HIST_OFF  4816896u     // hist[3][64][128][256] bf16, 12582912 B
#define CB_OFF    17399808u    // chars bf16 fragment tiles [8][512][4096], 33554432 B
#define NEED_MID  17399808ull
#define NEED_FULL 50954240ull
// legacy path reuses WT/GC and a ring at the old offset (exclusive with persistent path)
#define RING_OFF  4718592u

__device__ __forceinline__ ushort f2bf(float f) {
    uint32_t u = __float_as_uint(f);
    uint32_t r = u + 0x7FFFu + ((u >> 16) & 1u);
    return (ushort)(r >> 16);
}
__device__ __forceinline__ float sigmoidf_(float x) { return 1.0f / (1.0f + __expf(-x)); }

__device__ __forceinline__ void spin_ge(int* p, int v) {
    while (__hip_atomic_load(p, __ATOMIC_RELAXED, __HIP_MEMORY_SCOPE_AGENT) < v) {}
}

// ---------------- phase 0a: weight prep (fp32 -> bf16, [col][k], gate-cols permuted)
__global__ void k_prep(const float* __restrict__ w0, const float* __restrict__ w1,
                       const float* __restrict__ w2, ushort* __restrict__ wt) {
    int idx = blockIdx.x * 256 + threadIdx.x;
    if (idx >= 1769472) return;
    int e, Ks, cols; const float* W;
    if (idx < 393216)      { e = idx;          Ks = 512;  cols = 1024; W = w0; }
    else if (idx < 983040) { e = idx - 393216; Ks = 768;  cols = 1280; W = w1; }
    else                   { e = idx - 983040; Ks = 1024; cols = 1536; W = w2; }
    int c = e / Ks, k = e % Ks;
    int b = c / 96, cc = c % 96, g = cc >> 5, d32 = cc & 31;
    int j = g * 256 + b * 32 + d32;
    int scol = (k < 256) ? k : (512 + k);
    wt[idx] = f2bf(W[(size_t)j * cols + scol]);
}

// ---------------- phase 0b: gconst
__global__ void k_gconst(const float* __restrict__ w0, const float* __restrict__ w1, const float* __restrict__ w2,
                         const float* __restrict__ bih0, const float* __restrict__ bih1, const float* __restrict__ bih2,
                         const float* __restrict__ bhh0, const float* __restrict__ bhh1, const float* __restrict__ bhh2,
                         const float* __restrict__ sent, const float* __restrict__ ctx,
                         float* __restrict__ gc) {
    int idx = blockIdx.x * 256 + threadIdx.x;
    if (idx >= 3 * 768 * 128) return;
    int n = idx & 127;
    int scc = idx >> 7;
    int c = scc % 768, s = scc / 768;
    const float* W   = (s == 0) ? w0 : ((s == 1) ? w1 : w2);
    const float* bih = (s == 0) ? bih0 : ((s == 1) ? bih1 : bih2);
    const float* bhh = (s == 0) ? bhh0 : ((s == 1) ? bhh1 : bhh2);
    int cols = 1024 + 256 * s;
    int b = c / 96, cc = c % 96, g = cc >> 5, d32 = cc & 31;
    int j = g * 256 + b * 32 + d32;
    float acc = bih[j] + ((g < 2) ? bhh[j] : 0.0f);
    const float4* wr4 = (const float4*)(W + (size_t)j * cols + 256);
    const float4* sn4 = (const float4*)(sent + (size_t)n * 256);
    const float4* cx4 = (const float4*)(ctx + (size_t)n * 256);
    #pragma unroll 4
    for (int k = 0; k < 64; k++) {
        float4 wv = wr4[k], sv = sn4[k];
        acc += wv.x * sv.x + wv.y * sv.y + wv.z * sv.z + wv.w * sv.w;
    }
    #pragma unroll 4
    for (int k = 0; k < 64; k++) {
        float4 wv = wr4[64 + k], cv = cx4[k];
        acc += wv.x * cv.x + wv.y * cv.y + wv.z * cv.z + wv.w * cv.w;
    }
    gc[(size_t)(s * 128 + n) * 768 + c] = acc;
}

// ---------------- phase 0c: chars -> bf16 fragment tiles cb[g][t][4096]
__global__ void k_cprep(const float* __restrict__ chars, ushort* __restrict__ cb) {
    int idx = blockIdx.x * 256 + threadIdx.x;   // ((g*512 + t)*512 + q)
    if (idx >= 2097152) return;
    int q = idx & 511;
    int gt = idx >> 9;
    int t = gt & 511, g = gt >> 9;
    int r = q >> 5, ko = (q & 31) << 3;
    int n = g * 16 + r;
    const float* src = chars + ((size_t)n * T_STEPS + t) * 256 + ko;
    float4 f0 = *(const float4*)src;
    float4 f1 = *(const float4*)(src + 4);
    union { ushort u[8]; uint4 v; } pk;
    pk.u[0] = f2bf(f0.x); pk.u[1] = f2bf(f0.y); pk.u[2] = f2bf(f0.z); pk.u[3] = f2bf(f0.w);
    pk.u[4] = f2bf(f1.x); pk.u[5] = f2bf(f1.y); pk.u[6] = f2bf(f1.z); pk.u[7] = f2bf(f1.w);
    int pos = (ko >> 5) * 512 + (r + 16 * ((ko >> 3) & 3)) * 8;
    *(uint4*)(cb + (size_t)gt * 4096 + pos) = pk.v;
}

// ---------------- persistent dataflow kernel: 192 WGs = 3 stages x 8 groups x 8 col-blocks
__global__ void __launch_bounds__(128) k_run(
    const float* __restrict__ chars, const ushort* __restrict__ cb, int use_cb,
    const ushort* __restrict__ wt, const float* __restrict__ gc,
    ushort* __restrict__ hist, int* __restrict__ flag, int* __restrict__ cons,
    const float* __restrict__ bhh0, const float* __restrict__ bhh1, const float* __restrict__ bhh2,
    const float* __restrict__ hw0, const float* __restrict__ hw1, const float* __restrict__ hw2,
    const float* __restrict__ hb0, const float* __restrict__ hb1, const float* __restrict__ hb2,
    float* __restrict__ out) {
    __shared__ ushort Alds[16384];
    __shared__ float  glds[16 * 96];

    int bx = blockIdx.x;
    int s  = bx >> 6;
    int r2 = bx & 63;
    int g  = r2 >> 3;
    int b  = r2 & 7;
    int Ks = 512 + 256 * s;
    const ushort* wts = wt + ((s == 0) ? 0 : ((s == 1) ? 393216 : 983040));
    int tid = threadIdx.x;
    int w = tid >> 6, lane = tid & 63;
    const int CONS_FULL = (s == 0) ? 24 : ((s == 1) ? 16 : 8);
    const float* bhh = (s == 0) ? bhh0 : ((s == 1) ? bhh1 : bhh2);
    const float* hw  = (s == 0) ? hw0  : ((s == 1) ? hw1  : hw2);
    const float* hb  = (s == 0) ? hb0  : ((s == 1) ? hb1  : hb2);

    // per-thread invariant addressing for MFMA B operand (L2-resident slice)
    const ushort* bp0 = wts + (size_t)(b * 96 + w * 48 + (lane & 15)) * Ks + ((lane >> 4) << 3);
    const ushort* bp1 = bp0 + 16 * (size_t)Ks;
    const ushort* bp2 = bp0 + 32 * (size_t)Ks;
    const ushort* ap  = Alds + lane * 8;
    int nk = Ks >> 5;

    for (int t = 0; t < T_STEPS; ++t) {
        // ---- waits
        if (tid == 0) {
            if (t > 0)   spin_ge(&flag[((s * 512) + (t - 1)) * 8 + g], 8);
            if (s >= 1)  spin_ge(&flag[(((s - 1) * 512) + t) * 8 + g], 8);
            if (s == 2)  spin_ge(&flag[t * 8 + g], 8);
            if (t >= RSLOTS) spin_ge(&cons[((s * 512) + (t - RSLOTS)) * 8 + g], CONS_FULL);
        }
        __syncthreads();
        asm volatile("" ::: "memory");

        // ---- stage A: char part
        if (use_cb) {
            const uint4* src = (const uint4*)(cb + ((size_t)(g * 512 + t)) * 4096);
            uint4* dst = (uint4*)Alds;
            #pragma unroll
            for (int i = 0; i < 4; i++) dst[tid + 128 * i] = src[tid + 128 * i];
        } else {
            #pragma unroll
            for (int i = 0; i < 4; i++) {
                int q  = tid + 128 * i;
                int r  = q >> 5;
                int ko = (q & 31) << 3;
                int n  = g * 16 + r;
                const float* src = chars + ((size_t)n * T_STEPS + t) * 256 + ko;
                float4 f0 = *(const float4*)src;
                float4 f1 = *(const float4*)(src + 4);
                union { ushort u[8]; uint4 v; } pk;
                pk.u[0] = f2bf(f0.x); pk.u[1] = f2bf(f0.y); pk.u[2] = f2bf(f0.z); pk.u[3] = f2bf(f0.w);
                pk.u[4] = f2bf(f1.x); pk.u[5] = f2bf(f1.y); pk.u[6] = f2bf(f1.z); pk.u[7] = f2bf(f1.w);
                int pos = (ko >> 5) * 512 + (r + 16 * ((ko >> 3) & 3)) * 8;
                *(uint4*)(Alds + pos) = pk.v;
            }
        }
        // ---- stage A: h parts (agent-scope coherent loads; no cache-invalidating fence)
        for (int p = 0; p <= s; p++) {
            int tp = (p == s) ? (t - 1) : t;
            #pragma unroll
            for (int i = 0; i < 4; i++) {
                int q  = tid + 128 * i;
                int r  = q >> 5;
                int ko = (q & 31) << 3;
                int n  = g * 16 + r;
                int kg = 256 + p * 256 + ko;
                int pos = (kg >> 5) * 512 + (r + 16 * ((ko >> 3) & 3)) * 8;
                if (tp < 0) {
                    *(ull*)(Alds + pos) = 0ull;
                    *(ull*)(Alds + pos + 4) = 0ull;
                } else {
                    const ull* hp = (const ull*)(hist + (((size_t)p * RSLOTS + (tp & (RSLOTS - 1))) * 128 + n) * 256 + ko);
                    ull lo = __hip_atomic_load(hp,     __ATOMIC_RELAXED, __HIP_MEMORY_SCOPE_AGENT);
                    ull hi = __hip_atomic_load(hp + 1, __ATOMIC_RELAXED, __HIP_MEMORY_SCOPE_AGENT);
                    *(ull*)(Alds + pos) = lo;
                    *(ull*)(Alds + pos + 4) = hi;
                }
            }
        }
        __syncthreads();

        // ---- consumption acks (reads of hist are complete: barrier drained all waves)
        if (tid == 0) {
            if (t > 0)  __hip_atomic_fetch_add(&cons[((s * 512) + (t - 1)) * 8 + g], 1, __ATOMIC_RELAXED, __HIP_MEMORY_SCOPE_AGENT);
            if (s >= 1) __hip_atomic_fetch_add(&cons[t * 8 + g], 1, __ATOMIC_RELAXED, __HIP_MEMORY_SCOPE_AGENT);
            if (s == 2) __hip_atomic_fetch_add(&cons[(512 + t) * 8 + g], 1, __ATOMIC_RELAXED, __HIP_MEMORY_SCOPE_AGENT);
        }

        // ---- MFMA [16 x Ks] @ [Ks x 96]
        f32x4 acc0 = {0.f,0.f,0.f,0.f}, acc1 = {0.f,0.f,0.f,0.f}, acc2 = {0.f,0.f,0.f,0.f};
        #pragma unroll 8
        for (int ks = 0; ks < nk; ks++) {
            bf16x8 a  = *(const bf16x8*)(ap + ks * 512);
            bf16x8 b0 = *(const bf16x8*)(bp0 + ks * 32);
            bf16x8 b1 = *(const bf16x8*)(bp1 + ks * 32);
            bf16x8 b2 = *(const bf16x8*)(bp2 + ks * 32);
            acc0 = __builtin_amdgcn_mfma_f32_16x16x32_bf16(a, b0, acc0, 0, 0, 0);
            acc1 = __builtin_amdgcn_mfma_f32_16x16x32_bf16(a, b1, acc1, 0, 0, 0);
            acc2 = __builtin_amdgcn_mfma_f32_16x16x32_bf16(a, b2, acc2, 0, 0, 0);
        }
        {
            int rbase = (lane >> 4) * 4;
            int c0 = w * 48 + (lane & 15);
            #pragma unroll
            for (int q = 0; q < 4; q++) {
                glds[(rbase + q) * 96 + c0]      = acc0[q];
                glds[(rbase + q) * 96 + c0 + 16] = acc1[q];
                glds[(rbase + q) * 96 + c0 + 32] = acc2[q];
            }
        }
        __syncthreads();

        // ---- gating + h publish + fused head partials
        {
            int sl = tid >> 3;
            int d0 = (tid & 7) * 4;
            int n  = g * 16 + sl;
            const float* gcp = gc + (size_t)(s * 128 + n) * 768 + b * 96;
            float y0 = 0.f, y1 = 0.f;
            union { ushort u[4]; ull v; } hpk;
            #pragma unroll
            for (int dd = 0; dd < 4; dd++) {
                int d32 = d0 + dd;
                int d   = b * 32 + d32;
                float rp = glds[sl * 96 + d32]      + gcp[d32];
                float zp = glds[sl * 96 + 32 + d32] + gcp[32 + d32];
                float np = glds[sl * 96 + 64 + d32] + gcp[64 + d32];
                float rg = sigmoidf_(rp);
                float zg = sigmoidf_(zp);
                float ng = tanhf(np + rg * bhh[512 + d]);
                float h  = (1.0f - zg) * ng;
                hpk.u[dd] = f2bf(h);
                y0 += h * hw[d];
                y1 += h * hw[256 + d];
            }
            ull* hp = (ull*)(hist + (((size_t)s * RSLOTS + (t & (RSLOTS - 1))) * 128 + n) * 256 + b * 32 + d0);
            __hip_atomic_store(hp, hpk.v, __ATOMIC_RELAXED, __HIP_MEMORY_SCOPE_AGENT);
            y0 += __shfl_xor(y0, 1); y0 += __shfl_xor(y0, 2); y0 += __shfl_xor(y0, 4);
            y1 += __shfl_xor(y1, 1); y1 += __shfl_xor(y1, 2); y1 += __shfl_xor(y1, 4);
            if ((tid & 7) == 0) {
                if (b == 0) { y0 += hb[0]; y1 += hb[1]; }
                int bb = n >> 3, cc = n & 7;
                atomicAdd(out + (size_t)s * 131072 + (size_t)((bb * 2 + 0) * 8 + cc) * 512 + t, y0);
                atomicAdd(out + (size_t)s * 131072 + (size_t)((bb * 2 + 1) * 8 + cc) * 512 + t, y1);
            }
        }
        __syncthreads();   // drains h stores (barrier implies vmcnt(0))
        if (tid == 0) {
            __hip_atomic_fetch_add(&flag[((s * 512) + t) * 8 + g], 1, __ATOMIC_RELEASE, __HIP_MEMORY_SCOPE_AGENT);
        }
    }
}

// ---------------- legacy pipelined step kernel (fallback when ws is small)
__global__ void __launch_bounds__(128) k_step(
    const float* __restrict__ chars, const ushort* __restrict__ wt,
    const float* __restrict__ gc, ushort* __restrict__ ring,
    const float* __restrict__ bhh0, const float* __restrict__ bhh1, const float* __restrict__ bhh2,
    const float* __restrict__ hw0, const float* __restrict__ hw1, const float* __restrict__ hw2,
    const float* __restrict__ hb0, const float* __restrict__ hb1, const float* __restrict__ hb2,
    float* __restrict__ out, int stepi) {
    __shared__ ushort Alds[16384];
    __shared__ float  glds[16 * 96];

    int bx = blockIdx.x;
    int s  = bx >> 6;
    int r2 = bx & 63;
    int mt = r2 >> 3;
    int nb = r2 & 7;
    int t  = stepi - s;
    if (t < 0 || t >= T_STEPS) return;

    int Ks = 512 + 256 * s;
    const ushort* wts = wt + ((s == 0) ? 0 : ((s == 1) ? 393216 : 983040));
    int tid = threadIdx.x;

    #pragma unroll
    for (int i = 0; i < 4; i++) {
        int q  = tid + 128 * i;
        int r  = q >> 5;
        int ko = (q & 31) << 3;
        int n  = mt * 16 + r;
        const float* src = chars + ((size_t)n * T_STEPS + t) * 256 + ko;
        float4 f0 = *(const float4*)src;
        float4 f1 = *(const float4*)(src + 4);
        union { ushort u[8]; uint4 v; } pk;
        pk.u[0] = f2bf(f0.x); pk.u[1] = f2bf(f0.y); pk.u[2] = f2bf(f0.z); pk.u[3] = f2bf(f0.w);
        pk.u[4] = f2bf(f1.x); pk.u[5] = f2bf(f1.y); pk.u[6] = f2bf(f1.z); pk.u[7] = f2bf(f1.w);
        int pos = (ko >> 5) * 512 + (r + 16 * ((ko >> 3) & 3)) * 8;
        *(uint4*)(Alds + pos) = pk.v;
    }
    int nparts = s + 1;
    for (int p = 0; p < nparts; p++) {
        int slot = (p == s) ? ((t - 1) & 3) : (t & 3);
        const ushort* hsrc = ring + ((size_t)p * 4 + slot) * (128 * 256);
        #pragma unroll
        for (int i = 0; i < 4; i++) {
            int q  = tid + 128 * i;
            int r  = q >> 5;
            int ko = (q & 31) << 3;
            int n  = mt * 16 + r;
            uint4 v = *(const uint4*)(hsrc + (size_t)n * 256 + ko);
            int kg  = 256 + p * 256 + ko;
            int pos = (kg >> 5) * 512 + (r + 16 * ((kg >> 3) & 3)) * 8;
            *(uint4*)(Alds + pos) = v;
        }
    }
    __syncthreads();

    int w = tid >> 6, lane = tid & 63;
    int cbcol = nb * 96 + w * 48;
    f32x4 acc0 = {0.f,0.f,0.f,0.f}, acc1 = {0.f,0.f,0.f,0.f}, acc2 = {0.f,0.f,0.f,0.f};
    const ushort* bp0 = wts + (size_t)(cbcol + (lane & 15)) * Ks + ((lane >> 4) << 3);
    const ushort* bp1 = bp0 + 16 * (size_t)Ks;
    const ushort* bp2 = bp0 + 32 * (size_t)Ks;
    const ushort* ap  = Alds + lane * 8;
    int nk = Ks >> 5;
    #pragma unroll 8
    for (int ks = 0; ks < nk; ks++) {
        bf16x8 a  = *(const bf16x8*)(ap + ks * 512);
        bf16x8 b0 = *(const bf16x8*)(bp0 + ks * 32);
        bf16x8 b1 = *(const bf16x8*)(bp1 + ks * 32);
        bf16x8 b2 = *(const bf16x8*)(bp2 + ks * 32);
        acc0 = __builtin_amdgcn_mfma_f32_16x16x32_bf16(a, b0, acc0, 0, 0, 0);
        acc1 = __builtin_amdgcn_mfma_f32_16x16x32_bf16(a, b1, acc1, 0, 0, 0);
        acc2 = __builtin_amdgcn_mfma_f32_16x16x32_bf16(a, b2, acc2, 0, 0, 0);
    }
    {
        int rbase = (lane >> 4) * 4;
        int c0 = w * 48 + (lane & 15);
        #pragma unroll
        for (int q = 0; q < 4; q++) {
            glds[(rbase + q) * 96 + c0]      = acc0[q];
            glds[(rbase + q) * 96 + c0 + 16] = acc1[q];
            glds[(rbase + q) * 96 + c0 + 32] = acc2[q];
        }
    }
    __syncthreads();

    {
        int sl = tid >> 3;
        int d0 = (tid & 7) * 4;
        int n  = mt * 16 + sl;
        const float* bhh = (s == 0) ? bhh0 : ((s == 1) ? bhh1 : bhh2);
        const float* hw  = (s == 0) ? hw0  : ((s == 1) ? hw1  : hw2);
        const float* hb  = (s == 0) ? hb0  : ((s == 1) ? hb1  : hb2);
        const float* gcp = gc + (size_t)(s * 128 + n) * 768 + nb * 96;
        float y0 = 0.f, y1 = 0.f;
        union { ushort u[4]; uint2 v; } hpk;
        #pragma unroll
        for (int dd = 0; dd < 4; dd++) {
            int d32 = d0 + dd;
            int d   = nb * 32 + d32;
            float rp = glds[sl * 96 + d32]      + gcp[d32];
            float zp = glds[sl * 96 + 32 + d32] + gcp[32 + d32];
            float np = glds[sl * 96 + 64 + d32] + gcp[64 + d32];
            float rg = sigmoidf_(rp);
            float zg = sigmoidf_(zp);
            float ng = tanhf(np + rg * bhh[512 + d]);
            float h  = (1.0f - zg) * ng;
            hpk.u[dd] = f2bf(h);
            y0 += h * hw[d];
            y1 += h * hw[256 + d];
        }
        *(uint2*)(ring + (((size_t)s * 4 + (t & 3)) * 128 + n) * 256 + nb * 32 + d0) = hpk.v;
        y0 += __shfl_xor(y0, 1); y0 += __shfl_xor(y0, 2); y0 += __shfl_xor(y0, 4);
        y1 += __shfl_xor(y1, 1); y1 += __shfl_xor(y1, 2); y1 += __shfl_xor(y1, 4);
        if ((tid & 7) == 0) {
            if (nb == 0) { y0 += hb[0]; y1 += hb[1]; }
            int bb = n >> 3, cc = n & 7;
            atomicAdd(out + (size_t)s * 131072 + (size_t)((bb * 2 + 0) * 8 + cc) * 512 + t, y0);
            atomicAdd(out + (size_t)s * 131072 + (size_t)((bb * 2 + 1) * 8 + cc) * 512 + t, y1);
        }
    }
}

extern "C" void kernel_launch(void* const* d_in, const int* in_sizes, int n_in,
                              void* d_out, int out_size, void* d_ws, size_t ws_size,
                              hipStream_t stream) {
    const float* chars = (const float*)d_in[0];
    const float* sent  = (const float*)d_in[1];
    const float* ctx   = (const float*)d_in[2];
    const float* w0    = (const float*)d_in[3];
    const float* bih0  = (const float*)d_in[4];
    const float* bhh0  = (const float*)d_in[5];
    const float* w1    = (const float*)d_in[6];
    const float* bih1  = (const float*)d_in[7];
    const float* bhh1  = (const float*)d_in[8];
    const float* w2    = (const float*)d_in[9];
    const float* bih2  = (const float*)d_in[10];
    const float* bhh2  = (const float*)d_in[11];
    const float* hw0   = (const float*)d_in[12];
    const float* hb0   = (const float*)d_in[13];
    const float* hw1   = (const float*)d_in[14];
    const float* hb1   = (const float*)d_in[15];
    const float* hw2   = (const float*)d_in[16];
    const float* hb2   = (const float*)d_in[17];

    char* ws = (char*)d_ws;
    ushort* wt   = (ushort*)(ws + WT_OFF);
    float*  gcb  = (float*)(ws + GC_OFF);
    float*  out  = (float*)d_out;

    hipMemsetAsync(d_out, 0, (size_t)out_size * sizeof(float), stream);
    k_prep<<<6912, 256, 0, stream>>>(w0, w1, w2, wt);
    k_gconst<<<1152, 256, 0, stream>>>(w0, w1, w2, bih0, bih1, bih2,
                                       bhh0, bhh1, bhh2, sent, ctx, gcb);

    if (ws_size >= NEED_MID) {
        int*    flag = (int*)(ws + FLAG_OFF);
        int*    cons = (int*)(ws + CONS_OFF);
        ushort* hist = (ushort*)(ws + HIST_OFF);
        ushort* cbuf = (ushort*)(ws + CB_OFF);
        int use_cb = (ws_size >= NEED_FULL) ? 1 : 0;
        hipMemsetAsync(ws + FLAG_OFF, 0, 98304, stream);
        if (use_cb) k_cprep<<<8192, 256, 0, stream>>>(chars, cbuf);
        k_run<<<192, 128, 0, stream>>>(chars, use_cb ? cbuf : (const ushort*)nullptr, use_cb,
                                       wt, gcb, hist, flag, cons,
                                       bhh0, bhh1, bhh2, hw0, hw1, hw2,
                                       hb0, hb1, hb2, out);
    } else {
        ushort* ring = (ushort*)(ws + RING_OFF);
        hipMemsetAsync(ring, 0, (size_t)3 * 4 * 128 * 256 * 2, stream);
        for (int i = 0; i < T_STEPS + 2; i++) {
            k_step<<<192, 128, 0, stream>>>(chars, wt, gcb, ring,
                                            bhh0, bhh1, bhh2, hw0, hw1, hw2,
                                            hb0, hb1, hb2, out, i);
        }
    }
}

// Round 4
// 7690.082 us; speedup vs baseline: 1.1900x; 1.1900x over previous
//
#include <hip/hip_runtime.h>
#include <hip/hip_bf16.h>
#include <stdint.h>

typedef __attribute__((ext_vector_type(8))) short bf16x8;
typedef __attribute__((ext_vector_type(4))) float f32x4;
typedef unsigned long long ull;

// ---- problem constants ----
#define N_SAMP 128
#define T_STEPS 512
#define RSLOTS 64
#define GL 100   // padded glds row stride (floats)

// ---- ws layout (bytes) ----
#define WT_OFF    0u           // bf16 weights, 3538944 B
#define GC_OFF    3538944u     // gconst fp32, 1179648 B
#define FLAG_OFF  4718592u     // flag[3][512][8] int, 49152 B
#define CONS_OFF  4767744u     // cons[3][512][8] int, 49152 B
#define HIST_OFF  4816896u     // hist[3][64][128][256] bf16, 12582912 B
#define CB_OFF    17399808u    // chars bf16 fragment tiles [8][512][4096], 33554432 B
#define NEED_MID  17399808ull
#define NEED_FULL 50954240ull
#define RING_OFF  4718592u     // legacy fallback ring (exclusive with persistent path)

__device__ __forceinline__ ushort f2bf(float f) {
    uint32_t u = __float_as_uint(f);
    uint32_t r = u + 0x7FFFu + ((u >> 16) & 1u);
    return (ushort)(r >> 16);
}
__device__ __forceinline__ float sigmoidf_(float x) { return 1.0f / (1.0f + __expf(-x)); }

__device__ __forceinline__ void spin_ge(int* p, int v) {
    while (__hip_atomic_load(p, __ATOMIC_RELAXED, __HIP_MEMORY_SCOPE_AGENT) < v) {}
}

// LLC-coherent 16B load (bypass L1+L2: reads the coherence point; safe cross-XCD)
__device__ __forceinline__ void llc_load16(uint4& dst, const void* p) {
    asm volatile("global_load_dwordx4 %0, %1, off sc0 sc1" : "=&v"(dst) : "v"(p) : "memory");
}
// LLC write-through 8B store (data lands at coherence point; vmcnt(0) => globally visible)
__device__ __forceinline__ void llc_store8(void* p, ull v) {
    asm volatile("global_store_dwordx2 %0, %1, off sc0 sc1" :: "v"(p), "v"(v) : "memory");
}

// ---------------- phase 0a: weight prep (fp32 -> bf16, [col][k], gate-cols permuted)
__global__ void k_prep(const float* __restrict__ w0, const float* __restrict__ w1,
                       const float* __restrict__ w2, ushort* __restrict__ wt) {
    int idx = blockIdx.x * 256 + threadIdx.x;
    if (idx >= 1769472) return;
    int e, Ks, cols; const float* W;
    if (idx < 393216)      { e = idx;          Ks = 512;  cols = 1024; W = w0; }
    else if (idx < 983040) { e = idx - 393216; Ks = 768;  cols = 1280; W = w1; }
    else                   { e = idx - 983040; Ks = 1024; cols = 1536; W = w2; }
    int c = e / Ks, k = e % Ks;
    int b = c / 96, cc = c % 96, g = cc >> 5, d32 = cc & 31;
    int j = g * 256 + b * 32 + d32;
    int scol = (k < 256) ? k : (512 + k);
    wt[idx] = f2bf(W[(size_t)j * cols + scol]);
}

// ---------------- phase 0b: gconst
__global__ void k_gconst(const float* __restrict__ w0, const float* __restrict__ w1, const float* __restrict__ w2,
                         const float* __restrict__ bih0, const float* __restrict__ bih1, const float* __restrict__ bih2,
                         const float* __restrict__ bhh0, const float* __restrict__ bhh1, const float* __restrict__ bhh2,
                         const float* __restrict__ sent, const float* __restrict__ ctx,
                         float* __restrict__ gc) {
    int idx = blockIdx.x * 256 + threadIdx.x;
    if (idx >= 3 * 768 * 128) return;
    int n = idx & 127;
    int scc = idx >> 7;
    int c = scc % 768, s = scc / 768;
    const float* W   = (s == 0) ? w0 : ((s == 1) ? w1 : w2);
    const float* bih = (s == 0) ? bih0 : ((s == 1) ? bih1 : bih2);
    const float* bhh = (s == 0) ? bhh0 : ((s == 1) ? bhh1 : bhh2);
    int cols = 1024 + 256 * s;
    int b = c / 96, cc = c % 96, g = cc >> 5, d32 = cc & 31;
    int j = g * 256 + b * 32 + d32;
    float acc = bih[j] + ((g < 2) ? bhh[j] : 0.0f);
    const float4* wr4 = (const float4*)(W + (size_t)j * cols + 256);
    const float4* sn4 = (const float4*)(sent + (size_t)n * 256);
    const float4* cx4 = (const float4*)(ctx + (size_t)n * 256);
    #pragma unroll 4
    for (int k = 0; k < 64; k++) {
        float4 wv = wr4[k], sv = sn4[k];
        acc += wv.x * sv.x + wv.y * sv.y + wv.z * sv.z + wv.w * sv.w;
    }
    #pragma unroll 4
    for (int k = 0; k < 64; k++) {
        float4 wv = wr4[64 + k], cv = cx4[k];
        acc += wv.x * cv.x + wv.y * cv.y + wv.z * cv.z + wv.w * cv.w;
    }
    gc[(size_t)(s * 128 + n) * 768 + c] = acc;
}

// ---------------- phase 0c: chars -> bf16 fragment tiles cb[g][t][4096]
__global__ void k_cprep(const float* __restrict__ chars, ushort* __restrict__ cb) {
    int idx = blockIdx.x * 256 + threadIdx.x;
    if (idx >= 2097152) return;
    int q = idx & 511;
    int gt = idx >> 9;
    int t = gt & 511, g = gt >> 9;
    int r = q >> 5, ko = (q & 31) << 3;
    int n = g * 16 + r;
    const float* src = chars + ((size_t)n * T_STEPS + t) * 256 + ko;
    float4 f0 = *(const float4*)src;
    float4 f1 = *(const float4*)(src + 4);
    union { ushort u[8]; uint4 v; } pk;
    pk.u[0] = f2bf(f0.x); pk.u[1] = f2bf(f0.y); pk.u[2] = f2bf(f0.z); pk.u[3] = f2bf(f0.w);
    pk.u[4] = f2bf(f1.x); pk.u[5] = f2bf(f1.y); pk.u[6] = f2bf(f1.z); pk.u[7] = f2bf(f1.w);
    int pos = (ko >> 5) * 512 + (r + 16 * ((ko >> 3) & 3)) * 8;
    *(uint4*)(cb + (size_t)gt * 4096 + pos) = pk.v;
}

// ---------------- persistent dataflow kernel: 192 WGs = 3 stages x 8 groups x 8 col-blocks
__global__ void __launch_bounds__(128) k_run(
    const float* __restrict__ chars, const ushort* __restrict__ cb, int use_cb,
    const ushort* __restrict__ wt, const float* __restrict__ gc,
    ushort* __restrict__ hist, int* __restrict__ flag, int* __restrict__ cons,
    const float* __restrict__ bhh0, const float* __restrict__ bhh1, const float* __restrict__ bhh2,
    const float* __restrict__ hw0, const float* __restrict__ hw1, const float* __restrict__ hw2,
    const float* __restrict__ hb0, const float* __restrict__ hb1, const float* __restrict__ hb2,
    float* __restrict__ out) {
    __shared__ ushort Alds[16384];
    __shared__ float  glds[16 * GL];

    int bx = blockIdx.x;
    int s  = bx >> 6;
    int r2 = bx & 63;
    int g  = r2 >> 3;
    int b  = r2 & 7;
    int Ks = 512 + 256 * s;
    const ushort* wts = wt + ((s == 0) ? 0 : ((s == 1) ? 393216 : 983040));
    int tid = threadIdx.x;
    int w = tid >> 6, lane = tid & 63;
    const int CONS_FULL = (s == 0) ? 24 : ((s == 1) ? 16 : 8);
    const float* bhh = (s == 0) ? bhh0 : ((s == 1) ? bhh1 : bhh2);
    const float* hw  = (s == 0) ? hw0  : ((s == 1) ? hw1  : hw2);
    const float* hb  = (s == 0) ? hb0  : ((s == 1) ? hb1  : hb2);

    const ushort* bp0 = wts + (size_t)(b * 96 + w * 48 + (lane & 15)) * Ks + ((lane >> 4) << 3);
    const ushort* bp1 = bp0 + 16 * (size_t)Ks;
    const ushort* bp2 = bp0 + 32 * (size_t)Ks;
    const ushort* ap  = Alds + lane * 8;

    for (int t = 0; t < T_STEPS; ++t) {
        // ---- (W) waits: producer flags + backpressure (tid0 only)
        if (tid == 0) {
            if (t > 0)  spin_ge(&flag[((s * 512) + (t - 1)) * 8 + g], 8);
            if (s >= 1) spin_ge(&flag[(((s - 1) * 512) + t) * 8 + g], 8);
            if (s == 2) spin_ge(&flag[t * 8 + g], 8);
            if (t >= RSLOTS) spin_ge(&cons[((s * 512) + (t - RSLOTS)) * 8 + g], CONS_FULL);
        }
        // ---- (C) stage char part into Alds
        if (use_cb) {
            const uint4* src = (const uint4*)(cb + ((size_t)(g * 512 + t)) * 4096);
            uint4* dst = (uint4*)Alds;
            #pragma unroll
            for (int i = 0; i < 4; i++) dst[tid + 128 * i] = src[tid + 128 * i];
        } else {
            #pragma unroll
            for (int i = 0; i < 4; i++) {
                int q  = tid + 128 * i;
                int r  = q >> 5;
                int ko = (q & 31) << 3;
                int n  = g * 16 + r;
                const float* src = chars + ((size_t)n * T_STEPS + t) * 256 + ko;
                float4 f0 = *(const float4*)src;
                float4 f1 = *(const float4*)(src + 4);
                union { ushort u[8]; uint4 v; } pk;
                pk.u[0] = f2bf(f0.x); pk.u[1] = f2bf(f0.y); pk.u[2] = f2bf(f0.z); pk.u[3] = f2bf(f0.w);
                pk.u[4] = f2bf(f1.x); pk.u[5] = f2bf(f1.y); pk.u[6] = f2bf(f1.z); pk.u[7] = f2bf(f1.w);
                int pos = (ko >> 5) * 512 + (r + 16 * ((ko >> 3) & 3)) * 8;
                *(uint4*)(Alds + pos) = pk.v;
            }
        }
        __syncthreads();   // B1: chars staged, flags seen

        // ---- (L) issue ALL h-part loads (LLC-coherent), batched, no per-load waits
        uint4 h0[4], h1[4], h2[4];
        #pragma unroll
        for (int i = 0; i < 4; i++) {
            int q = tid + 128 * i; int r = q >> 5; int ko = (q & 31) << 3;
            int n = g * 16 + r;
            int tp0 = (0 == s) ? (t - 1) : t;
            if (tp0 >= 0)
                llc_load16(h0[i], hist + (((size_t)0 * RSLOTS + (tp0 & 63)) * 128 + n) * 256 + ko);
        }
        if (s >= 1) {
            #pragma unroll
            for (int i = 0; i < 4; i++) {
                int q = tid + 128 * i; int r = q >> 5; int ko = (q & 31) << 3;
                int n = g * 16 + r;
                int tp1 = (1 == s) ? (t - 1) : t;
                if (tp1 >= 0)
                    llc_load16(h1[i], hist + (((size_t)1 * RSLOTS + (tp1 & 63)) * 128 + n) * 256 + ko);
            }
        }
        if (s == 2) {
            #pragma unroll
            for (int i = 0; i < 4; i++) {
                int q = tid + 128 * i; int r = q >> 5; int ko = (q & 31) << 3;
                int n = g * 16 + r;
                int tp2 = t - 1;
                if (tp2 >= 0)
                    llc_load16(h2[i], hist + (((size_t)2 * RSLOTS + (tp2 & 63)) * 128 + n) * 256 + ko);
            }
        }

        // ---- (M1) char-part MFMA (k in [0,256)) — hides h-load latency
        f32x4 acc0 = {0.f,0.f,0.f,0.f}, acc1 = {0.f,0.f,0.f,0.f}, acc2 = {0.f,0.f,0.f,0.f};
        #pragma unroll
        for (int ks = 0; ks < 8; ks++) {
            bf16x8 a  = *(const bf16x8*)(ap + ks * 512);
            bf16x8 b0 = *(const bf16x8*)(bp0 + ks * 32);
            bf16x8 b1 = *(const bf16x8*)(bp1 + ks * 32);
            bf16x8 b2 = *(const bf16x8*)(bp2 + ks * 32);
            acc0 = __builtin_amdgcn_mfma_f32_16x16x32_bf16(a, b0, acc0, 0, 0, 0);
            acc1 = __builtin_amdgcn_mfma_f32_16x16x32_bf16(a, b1, acc1, 0, 0, 0);
            acc2 = __builtin_amdgcn_mfma_f32_16x16x32_bf16(a, b2, acc2, 0, 0, 0);
        }

        // ---- single wait for all h loads, then stage into Alds
        asm volatile("s_waitcnt vmcnt(0)" ::: "memory");
        __builtin_amdgcn_sched_barrier(0);
        {
            #pragma unroll
            for (int i = 0; i < 4; i++) {
                int q = tid + 128 * i; int r = q >> 5; int ko = (q & 31) << 3;
                int kg = 256 + ko;
                int pos = (kg >> 5) * 512 + (r + 16 * ((ko >> 3) & 3)) * 8;
                int tp0 = (0 == s) ? (t - 1) : t;
                if (tp0 >= 0) *(uint4*)(Alds + pos) = h0[i];
                else { uint4 z = {0,0,0,0}; *(uint4*)(Alds + pos) = z; }
            }
            if (s >= 1) {
                #pragma unroll
                for (int i = 0; i < 4; i++) {
                    int q = tid + 128 * i; int r = q >> 5; int ko = (q & 31) << 3;
                    int kg = 512 + ko;
                    int pos = (kg >> 5) * 512 + (r + 16 * ((ko >> 3) & 3)) * 8;
                    int tp1 = (1 == s) ? (t - 1) : t;
                    if (tp1 >= 0) *(uint4*)(Alds + pos) = h1[i];
                    else { uint4 z = {0,0,0,0}; *(uint4*)(Alds + pos) = z; }
                }
            }
            if (s == 2) {
                #pragma unroll
                for (int i = 0; i < 4; i++) {
                    int q = tid + 128 * i; int r = q >> 5; int ko = (q & 31) << 3;
                    int kg = 768 + ko;
                    int pos = (kg >> 5) * 512 + (r + 16 * ((ko >> 3) & 3)) * 8;
                    if (t >= 1) *(uint4*)(Alds + pos) = h2[i];
                    else { uint4 z = {0,0,0,0}; *(uint4*)(Alds + pos) = z; }
                }
            }
        }
        __syncthreads();   // B2: h staged

        // ---- consumption acks
        if (tid == 0) {
            if (t > 0)  __hip_atomic_fetch_add(&cons[((s * 512) + (t - 1)) * 8 + g], 1, __ATOMIC_RELAXED, __HIP_MEMORY_SCOPE_AGENT);
            if (s >= 1) __hip_atomic_fetch_add(&cons[t * 8 + g], 1, __ATOMIC_RELAXED, __HIP_MEMORY_SCOPE_AGENT);
            if (s == 2) __hip_atomic_fetch_add(&cons[(512 + t) * 8 + g], 1, __ATOMIC_RELAXED, __HIP_MEMORY_SCOPE_AGENT);
        }

        // ---- (M2) h-part MFMA (k in [256, Ks))
        #pragma unroll
        for (int p = 0; p < 3; p++) {
            if (p > s) continue;
            #pragma unroll
            for (int j = 0; j < 8; j++) {
                int ks = 8 + 8 * p + j;
                bf16x8 a  = *(const bf16x8*)(ap + ks * 512);
                bf16x8 b0 = *(const bf16x8*)(bp0 + ks * 32);
                bf16x8 b1 = *(const bf16x8*)(bp1 + ks * 32);
                bf16x8 b2 = *(const bf16x8*)(bp2 + ks * 32);
                acc0 = __builtin_amdgcn_mfma_f32_16x16x32_bf16(a, b0, acc0, 0, 0, 0);
                acc1 = __builtin_amdgcn_mfma_f32_16x16x32_bf16(a, b1, acc1, 0, 0, 0);
                acc2 = __builtin_amdgcn_mfma_f32_16x16x32_bf16(a, b2, acc2, 0, 0, 0);
            }
        }
        {
            int rbase = (lane >> 4) * 4;
            int c0 = w * 48 + (lane & 15);
            #pragma unroll
            for (int q = 0; q < 4; q++) {
                glds[(rbase + q) * GL + c0]      = acc0[q];
                glds[(rbase + q) * GL + c0 + 16] = acc1[q];
                glds[(rbase + q) * GL + c0 + 32] = acc2[q];
            }
        }
        __syncthreads();   // B3: gates ready

        // ---- gating + h publish (LLC write-through) + fused head partials
        {
            int sl = tid >> 3;
            int d0 = (tid & 7) * 4;
            int n  = g * 16 + sl;
            const float* gcp = gc + (size_t)(s * 128 + n) * 768 + b * 96;
            float y0 = 0.f, y1 = 0.f;
            union { ushort u[4]; ull v; } hpk;
            #pragma unroll
            for (int dd = 0; dd < 4; dd++) {
                int d32 = d0 + dd;
                int d   = b * 32 + d32;
                float rp = glds[sl * GL + d32]      + gcp[d32];
                float zp = glds[sl * GL + 32 + d32] + gcp[32 + d32];
                float np = glds[sl * GL + 64 + d32] + gcp[64 + d32];
                float rg = sigmoidf_(rp);
                float zg = sigmoidf_(zp);
                float ng = tanhf(np + rg * bhh[512 + d]);
                float h  = (1.0f - zg) * ng;
                hpk.u[dd] = f2bf(h);
                y0 += h * hw[d];
                y1 += h * hw[256 + d];
            }
            llc_store8(hist + (((size_t)s * RSLOTS + (t & 63)) * 128 + n) * 256 + b * 32 + d0, hpk.v);
            y0 += __shfl_xor(y0, 1); y0 += __shfl_xor(y0, 2); y0 += __shfl_xor(y0, 4);
            y1 += __shfl_xor(y1, 1); y1 += __shfl_xor(y1, 2); y1 += __shfl_xor(y1, 4);
            if ((tid & 7) == 0) {
                if (b == 0) { y0 += hb[0]; y1 += hb[1]; }
                int bb = n >> 3, cc = n & 7;
                atomicAdd(out + (size_t)s * 131072 + (size_t)((bb * 2 + 0) * 8 + cc) * 512 + t, y0);
                atomicAdd(out + (size_t)s * 131072 + (size_t)((bb * 2 + 1) * 8 + cc) * 512 + t, y1);
            }
        }
        __syncthreads();   // B4: publish drained (vmcnt(0) before s_barrier) -> h at LLC
        if (tid == 0) {
            __hip_atomic_fetch_add(&flag[((s * 512) + t) * 8 + g], 1, __ATOMIC_RELEASE, __HIP_MEMORY_SCOPE_AGENT);
        }
    }
}

// ---------------- legacy pipelined step kernel (fallback when ws is small)
__global__ void __launch_bounds__(128) k_step(
    const float* __restrict__ chars, const ushort* __restrict__ wt,
    const float* __restrict__ gc, ushort* __restrict__ ring,
    const float* __restrict__ bhh0, const float* __restrict__ bhh1, const float* __restrict__ bhh2,
    const float* __restrict__ hw0, const float* __restrict__ hw1, const float* __restrict__ hw2,
    const float* __restrict__ hb0, const float* __restrict__ hb1, const float* __restrict__ hb2,
    float* __restrict__ out, int stepi) {
    __shared__ ushort Alds[16384];
    __shared__ float  glds[16 * GL];

    int bx = blockIdx.x;
    int s  = bx >> 6;
    int r2 = bx & 63;
    int mt = r2 >> 3;
    int nb = r2 & 7;
    int t  = stepi - s;
    if (t < 0 || t >= T_STEPS) return;

    int Ks = 512 + 256 * s;
    const ushort* wts = wt + ((s == 0) ? 0 : ((s == 1) ? 393216 : 983040));
    int tid = threadIdx.x;

    #pragma unroll
    for (int i = 0; i < 4; i++) {
        int q  = tid + 128 * i;
        int r  = q >> 5;
        int ko = (q & 31) << 3;
        int n  = mt * 16 + r;
        const float* src = chars + ((size_t)n * T_STEPS + t) * 256 + ko;
        float4 f0 = *(const float4*)src;
        float4 f1 = *(const float4*)(src + 4);
        union { ushort u[8]; uint4 v; } pk;
        pk.u[0] = f2bf(f0.x); pk.u[1] = f2bf(f0.y); pk.u[2] = f2bf(f0.z); pk.u[3] = f2bf(f0.w);
        pk.u[4] = f2bf(f1.x); pk.u[5] = f2bf(f1.y); pk.u[6] = f2bf(f1.z); pk.u[7] = f2bf(f1.w);
        int pos = (ko >> 5) * 512 + (r + 16 * ((ko >> 3) & 3)) * 8;
        *(uint4*)(Alds + pos) = pk.v;
    }
    int nparts = s + 1;
    for (int p = 0; p < nparts; p++) {
        int slot = (p == s) ? ((t - 1) & 3) : (t & 3);
        const ushort* hsrc = ring + ((size_t)p * 4 + slot) * (128 * 256);
        #pragma unroll
        for (int i = 0; i < 4; i++) {
            int q  = tid + 128 * i;
            int r  = q >> 5;
            int ko = (q & 31) << 3;
            int n  = mt * 16 + r;
            uint4 v = *(const uint4*)(hsrc + (size_t)n * 256 + ko);
            int kg  = 256 + p * 256 + ko;
            int pos = (kg >> 5) * 512 + (r + 16 * ((kg >> 3) & 3)) * 8;
            *(uint4*)(Alds + pos) = v;
        }
    }
    __syncthreads();

    int w = tid >> 6, lane = tid & 63;
    int cbcol = nb * 96 + w * 48;
    f32x4 acc0 = {0.f,0.f,0.f,0.f}, acc1 = {0.f,0.f,0.f,0.f}, acc2 = {0.f,0.f,0.f,0.f};
    const ushort* bp0 = wts + (size_t)(cbcol + (lane & 15)) * Ks + ((lane >> 4) << 3);
    const ushort* bp1 = bp0 + 16 * (size_t)Ks;
    const ushort* bp2 = bp0 + 32 * (size_t)Ks;
    const ushort* ap  = Alds + lane * 8;
    int nk = Ks >> 5;
    #pragma unroll 8
    for (int ks = 0; ks < nk; ks++) {
        bf16x8 a  = *(const bf16x8*)(ap + ks * 512);
        bf16x8 b0 = *(const bf16x8*)(bp0 + ks * 32);
        bf16x8 b1 = *(const bf16x8*)(bp1 + ks * 32);
        bf16x8 b2 = *(const bf16x8*)(bp2 + ks * 32);
        acc0 = __builtin_amdgcn_mfma_f32_16x16x32_bf16(a, b0, acc0, 0, 0, 0);
        acc1 = __builtin_amdgcn_mfma_f32_16x16x32_bf16(a, b1, acc1, 0, 0, 0);
        acc2 = __builtin_amdgcn_mfma_f32_16x16x32_bf16(a, b2, acc2, 0, 0, 0);
    }
    {
        int rbase = (lane >> 4) * 4;
        int c0 = w * 48 + (lane & 15);
        #pragma unroll
        for (int q = 0; q < 4; q++) {
            glds[(rbase + q) * GL + c0]      = acc0[q];
            glds[(rbase + q) * GL + c0 + 16] = acc1[q];
            glds[(rbase + q) * GL + c0 + 32] = acc2[q];
        }
    }
    __syncthreads();

    {
        int sl = tid >> 3;
        int d0 = (tid & 7) * 4;
        int n  = mt * 16 + sl;
        const float* bhh = (s == 0) ? bhh0 : ((s == 1) ? bhh1 : bhh2);
        const float* hw  = (s == 0) ? hw0  : ((s == 1) ? hw1  : hw2);
        const float* hb  = (s == 0) ? hb0  : ((s == 1) ? hb1  : hb2);
        const float* gcp = gc + (size_t)(s * 128 + n) * 768 + nb * 96;
        float y0 = 0.f, y1 = 0.f;
        union { ushort u[4]; uint2 v; } hpk;
        #pragma unroll
        for (int dd = 0; dd < 4; dd++) {
            int d32 = d0 + dd;
            int d   = nb * 32 + d32;
            float rp = glds[sl * GL + d32]      + gcp[d32];
            float zp = glds[sl * GL + 32 + d32] + gcp[32 + d32];
            float np = glds[sl * GL + 64 + d32] + gcp[64 + d32];
            float rg = sigmoidf_(rp);
            float zg = sigmoidf_(zp);
            float ng = tanhf(np + rg * bhh[512 + d]);
            float h  = (1.0f - zg) * ng;
            hpk.u[dd] = f2bf(h);
            y0 += h * hw[d];
            y1 += h * hw[256 + d];
        }
        *(uint2*)(ring + (((size_t)s * 4 + (t & 3)) * 128 + n) * 256 + nb * 32 + d0) = hpk.v;
        y0 += __shfl_xor(y0, 1); y0 += __shfl_xor(y0, 2); y0 += __shfl_xor(y0, 4);
        y1 += __shfl_xor(y1, 1); y1 += __shfl_xor(y1, 2); y1 += __shfl_xor(y1, 4);
        if ((tid & 7) == 0) {
            if (nb == 0) { y0 += hb[0]; y1 += hb[1]; }
            int bb = n >> 3, cc = n & 7;
            atomicAdd(out + (size_t)s * 131072 + (size_t)((bb * 2 + 0) * 8 + cc) * 512 + t, y0);
            atomicAdd(out + (size_t)s * 131072 + (size_t)((bb * 2 + 1) * 8 + cc) * 512 + t, y1);
        }
    }
}

extern "C" void kernel_launch(void* const* d_in, const int* in_sizes, int n_in,
                              void* d_out, int out_size, void* d_ws, size_t ws_size,
                              hipStream_t stream) {
    const float* chars = (const float*)d_in[0];
    const float* sent  = (const float*)d_in[1];
    const float* ctx   = (const float*)d_in[2];
    const float* w0    = (const float*)d_in[3];
    const float* bih0  = (const float*)d_in[4];
    const float* bhh0  = (const float*)d_in[5];
    const float* w1    = (const float*)d_in[6];
    const float* bih1  = (const float*)d_in[7];
    const float* bhh1  = (const float*)d_in[8];
    const float* w2    = (const float*)d_in[9];
    const float* bih2  = (const float*)d_in[10];
    const float* bhh2  = (const float*)d_in[11];
    const float* hw0   = (const float*)d_in[12];
    const float* hb0   = (const float*)d_in[13];
    const float* hw1   = (const float*)d_in[14];
    const float* hb1   = (const float*)d_in[15];
    const float* hw2   = (const float*)d_in[16];
    const float* hb2   = (const float*)d_in[17];

    char* ws = (char*)d_ws;
    ushort* wt   = (ushort*)(ws + WT_OFF);
    float*  gcb  = (float*)(ws + GC_OFF);
    float*  out  = (float*)d_out;

    hipMemsetAsync(d_out, 0, (size_t)out_size * sizeof(float), stream);
    k_prep<<<6912, 256, 0, stream>>>(w0, w1, w2, wt);
    k_gconst<<<1152, 256, 0, stream>>>(w0, w1, w2, bih0, bih1, bih2,
                                       bhh0, bhh1, bhh2, sent, ctx, gcb);

    if (ws_size >= NEED_MID) {
        int*    flag = (int*)(ws + FLAG_OFF);
        int*    cons = (int*)(ws + CONS_OFF);
        ushort* hist = (ushort*)(ws + HIST_OFF);
        ushort* cbuf = (ushort*)(ws + CB_OFF);
        int use_cb = (ws_size >= NEED_FULL) ? 1 : 0;
        hipMemsetAsync(ws + FLAG_OFF, 0, 98304, stream);   // flag + cons
        if (use_cb) k_cprep<<<8192, 256, 0, stream>>>(chars, cbuf);
        k_run<<<192, 128, 0, stream>>>(chars, use_cb ? cbuf : (const ushort*)nullptr, use_cb,
                                       wt, gcb, hist, flag, cons,
                                       bhh0, bhh1, bhh2, hw0, hw1, hw2,
                                       hb0, hb1, hb2, out);
    } else {
        ushort* ring = (ushort*)(ws + RING_OFF);
        hipMemsetAsync(ring, 0, (size_t)3 * 4 * 128 * 256 * 2, stream);
        for (int i = 0; i < T_STEPS + 2; i++) {
            k_step<<<192, 128, 0, stream>>>(chars, wt, gcb, ring,
                                            bhh0, bhh1, bhh2, hw0, hw1, hw2,
                                            hb0, hb1, hb2, out, i);
        }
    }
}

// Round 6
// 6415.610 us; speedup vs baseline: 1.4264x; 1.1987x over previous
//
#include <hip/hip_runtime.h>
#include <hip/hip_bf16.h>
#include <stdint.h>

typedef __attribute__((ext_vector_type(8))) short bf16x8;
typedef __attribute__((ext_vector_type(4))) float f32x4;
typedef unsigned long long ull;

// ---- problem constants ----
#define N_SAMP 128
#define T_STEPS 512
#define RSLOTS 64
#define GL 100   // padded glds row stride (floats)

// ---- ws layout (bytes) ----
#define WT_OFF    0u           // bf16 weights, 3538944 B
#define GC_OFF    3538944u     // gconst fp32, 1179648 B
#define FLAG_OFF  4718592u     // flag[3][512][8] int, 49152 B
#define CONS_OFF  4767744u     // cons[3][512][8] int, 49152 B
#define HIST_OFF  4816896u     // hist[3][64][128][256] bf16, 12582912 B
#define CB_OFF    17399808u    // chars bf16 fragment tiles [8][512][4096], 33554432 B
#define NEED_MID  17399808ull
#define NEED_FULL 50954240ull
#define RING_OFF  4718592u     // legacy fallback ring (exclusive with persistent path)

__device__ __forceinline__ ushort f2bf(float f) {
    uint32_t u = __float_as_uint(f);
    uint32_t r = u + 0x7FFFu + ((u >> 16) & 1u);
    return (ushort)(r >> 16);
}
__device__ __forceinline__ float sigmoidf_(float x) { return 1.0f / (1.0f + __expf(-x)); }

// LLC-coherent 16B load (bypass L1+L2: reads the coherence point; safe cross-XCD)
__device__ __forceinline__ void llc_load16(uint4& dst, const void* p) {
    asm volatile("global_load_dwordx4 %0, %1, off sc0 sc1" : "=&v"(dst) : "v"(p) : "memory");
}
// LLC write-through 8B store (data lands at coherence point once vmcnt drains)
__device__ __forceinline__ void llc_store8(void* p, ull v) {
    asm volatile("global_store_dwordx2 %0, %1, off sc0 sc1" :: "v"(p), "v"(v) : "memory");
}
// Explicit per-wave drain of outstanding VMEM ops (compiler does NOT emit this for
// inline-asm stores before s_barrier — the r5 correctness hole).
__device__ __forceinline__ void drain_vmem() {
    asm volatile("s_waitcnt vmcnt(0)" ::: "memory");
}

// ---------------- phase 0a: weight prep (fp32 -> bf16, [col][k], gate-cols permuted)
__global__ void k_prep(const float* __restrict__ w0, const float* __restrict__ w1,
                       const float* __restrict__ w2, ushort* __restrict__ wt) {
    int idx = blockIdx.x * 256 + threadIdx.x;
    if (idx >= 1769472) return;
    int e, Ks, cols; const float* W;
    if (idx < 393216)      { e = idx;          Ks = 512;  cols = 1024; W = w0; }
    else if (idx < 983040) { e = idx - 393216; Ks = 768;  cols = 1280; W = w1; }
    else                   { e = idx - 983040; Ks = 1024; cols = 1536; W = w2; }
    int c = e / Ks, k = e % Ks;
    int b = c / 96, cc = c % 96, g = cc >> 5, d32 = cc & 31;
    int j = g * 256 + b * 32 + d32;
    int scol = (k < 256) ? k : (512 + k);
    wt[idx] = f2bf(W[(size_t)j * cols + scol]);
}

// ---------------- phase 0b: gconst
__global__ void k_gconst(const float* __restrict__ w0, const float* __restrict__ w1, const float* __restrict__ w2,
                         const float* __restrict__ bih0, const float* __restrict__ bih1, const float* __restrict__ bih2,
                         const float* __restrict__ bhh0, const float* __restrict__ bhh1, const float* __restrict__ bhh2,
                         const float* __restrict__ sent, const float* __restrict__ ctx,
                         float* __restrict__ gc) {
    int idx = blockIdx.x * 256 + threadIdx.x;
    if (idx >= 3 * 768 * 128) return;
    int n = idx & 127;
    int scc = idx >> 7;
    int c = scc % 768, s = scc / 768;
    const float* W   = (s == 0) ? w0 : ((s == 1) ? w1 : w2);
    const float* bih = (s == 0) ? bih0 : ((s == 1) ? bih1 : bih2);
    const float* bhh = (s == 0) ? bhh0 : ((s == 1) ? bhh1 : bhh2);
    int cols = 1024 + 256 * s;
    int b = c / 96, cc = c % 96, g = cc >> 5, d32 = cc & 31;
    int j = g * 256 + b * 32 + d32;
    float acc = bih[j] + ((g < 2) ? bhh[j] : 0.0f);
    const float4* wr4 = (const float4*)(W + (size_t)j * cols + 256);
    const float4* sn4 = (const float4*)(sent + (size_t)n * 256);
    const float4* cx4 = (const float4*)(ctx + (size_t)n * 256);
    #pragma unroll 4
    for (int k = 0; k < 64; k++) {
        float4 wv = wr4[k], sv = sn4[k];
        acc += wv.x * sv.x + wv.y * sv.y + wv.z * sv.z + wv.w * sv.w;
    }
    #pragma unroll 4
    for (int k = 0; k < 64; k++) {
        float4 wv = wr4[64 + k], cv = cx4[k];
        acc += wv.x * cv.x + wv.y * cv.y + wv.z * cv.z + wv.w * cv.w;
    }
    gc[(size_t)(s * 128 + n) * 768 + c] = acc;
}

// ---------------- phase 0c: chars -> bf16 fragment tiles cb[g][t][4096]
__global__ void k_cprep(const float* __restrict__ chars, ushort* __restrict__ cb) {
    int idx = blockIdx.x * 256 + threadIdx.x;
    if (idx >= 2097152) return;
    int q = idx & 511;
    int gt = idx >> 9;
    int t = gt & 511, g = gt >> 9;
    int r = q >> 5, ko = (q & 31) << 3;
    int n = g * 16 + r;
    const float* src = chars + ((size_t)n * T_STEPS + t) * 256 + ko;
    float4 f0 = *(const float4*)src;
    float4 f1 = *(const float4*)(src + 4);
    union { ushort u[8]; uint4 v; } pk;
    pk.u[0] = f2bf(f0.x); pk.u[1] = f2bf(f0.y); pk.u[2] = f2bf(f0.z); pk.u[3] = f2bf(f0.w);
    pk.u[4] = f2bf(f1.x); pk.u[5] = f2bf(f1.y); pk.u[6] = f2bf(f1.z); pk.u[7] = f2bf(f1.w);
    int pos = (ko >> 5) * 512 + (r + 16 * ((ko >> 3) & 3)) * 8;
    *(uint4*)(cb + (size_t)gt * 4096 + pos) = pk.v;
}

// ---------------- persistent dataflow kernel: 192 WGs = 3 stages x 8 groups x 8 col-blocks
__global__ void __launch_bounds__(128) k_run(
    const float* __restrict__ chars, const ushort* __restrict__ cb, int use_cb,
    const ushort* __restrict__ wt, const float* __restrict__ gc,
    ushort* __restrict__ hist, int* __restrict__ flag, int* __restrict__ cons,
    const float* __restrict__ bhh0, const float* __restrict__ bhh1, const float* __restrict__ bhh2,
    const float* __restrict__ hw0, const float* __restrict__ hw1, const float* __restrict__ hw2,
    const float* __restrict__ hb0, const float* __restrict__ hb1, const float* __restrict__ hb2,
    float* __restrict__ out) {
    __shared__ ushort Alds[16384];
    __shared__ float  glds[16 * GL];

    int bx = blockIdx.x;
    int s  = bx >> 6;
    int r2 = bx & 63;
    int g  = r2 >> 3;
    int b  = r2 & 7;
    int Ks = 512 + 256 * s;
    const ushort* wts = wt + ((s == 0) ? 0 : ((s == 1) ? 393216 : 983040));
    int tid = threadIdx.x;
    int w = tid >> 6, lane = tid & 63;
    const int CONS_FULL = (s == 0) ? 24 : ((s == 1) ? 16 : 8);
    const float* bhh = (s == 0) ? bhh0 : ((s == 1) ? bhh1 : bhh2);
    const float* hw  = (s == 0) ? hw0  : ((s == 1) ? hw1  : hw2);
    const float* hb  = (s == 0) ? hb0  : ((s == 1) ? hb1  : hb2);

    const ushort* bp0 = wts + (size_t)(b * 96 + w * 48 + (lane & 15)) * Ks + ((lane >> 4) << 3);
    const ushort* bp1 = bp0 + 16 * (size_t)Ks;
    const ushort* bp2 = bp0 + 32 * (size_t)Ks;
    const ushort* ap  = Alds + lane * 8;

    for (int t = 0; t < T_STEPS; ++t) {
        // ---- (W) waits: lanes 0..2 spin in PARALLEL (one exec pass)
        if (tid < 3) {
            int* p = nullptr; int want = 0;
            if (tid == 0 && t > 0)       { p = &flag[((s * 512) + (t - 1)) * 8 + g]; want = 8; }
            if (tid == 1 && s >= 1)      { p = &flag[(((s - 1) * 512) + t) * 8 + g]; want = 8; }
            if (tid == 2 && t >= RSLOTS) { p = &cons[((s * 512) + (t - RSLOTS)) * 8 + g]; want = CONS_FULL; }
            if (p) {
                while (__hip_atomic_load(p, __ATOMIC_RELAXED, __HIP_MEMORY_SCOPE_AGENT) < want) {}
            }
        }
        // ---- (C) stage char part into Alds
        if (use_cb) {
            const uint4* src = (const uint4*)(cb + ((size_t)(g * 512 + t)) * 4096);
            uint4* dst = (uint4*)Alds;
            #pragma unroll
            for (int i = 0; i < 4; i++) dst[tid + 128 * i] = src[tid + 128 * i];
        } else {
            #pragma unroll
            for (int i = 0; i < 4; i++) {
                int q  = tid + 128 * i;
                int r  = q >> 5;
                int ko = (q & 31) << 3;
                int n  = g * 16 + r;
                const float* src = chars + ((size_t)n * T_STEPS + t) * 256 + ko;
                float4 f0 = *(const float4*)src;
                float4 f1 = *(const float4*)(src + 4);
                union { ushort u[8]; uint4 v; } pk;
                pk.u[0] = f2bf(f0.x); pk.u[1] = f2bf(f0.y); pk.u[2] = f2bf(f0.z); pk.u[3] = f2bf(f0.w);
                pk.u[4] = f2bf(f1.x); pk.u[5] = f2bf(f1.y); pk.u[6] = f2bf(f1.z); pk.u[7] = f2bf(f1.w);
                int pos = (ko >> 5) * 512 + (r + 16 * ((ko >> 3) & 3)) * 8;
                *(uint4*)(Alds + pos) = pk.v;
            }
        }
        __syncthreads();   // B1: chars staged, flags observed (spinners gate everyone)

        // ---- (L) issue ALL h-part loads (LLC-coherent), batched, no per-load waits
        uint4 h0[4], h1[4], h2[4];
        #pragma unroll
        for (int i = 0; i < 4; i++) {
            int q = tid + 128 * i; int r = q >> 5; int ko = (q & 31) << 3;
            int n = g * 16 + r;
            int tp0 = (0 == s) ? (t - 1) : t;
            if (tp0 >= 0)
                llc_load16(h0[i], hist + (((size_t)0 * RSLOTS + (tp0 & 63)) * 128 + n) * 256 + ko);
        }
        if (s >= 1) {
            #pragma unroll
            for (int i = 0; i < 4; i++) {
                int q = tid + 128 * i; int r = q >> 5; int ko = (q & 31) << 3;
                int n = g * 16 + r;
                int tp1 = (1 == s) ? (t - 1) : t;
                if (tp1 >= 0)
                    llc_load16(h1[i], hist + (((size_t)1 * RSLOTS + (tp1 & 63)) * 128 + n) * 256 + ko);
            }
        }
        if (s == 2) {
            #pragma unroll
            for (int i = 0; i < 4; i++) {
                int q = tid + 128 * i; int r = q >> 5; int ko = (q & 31) << 3;
                int n = g * 16 + r;
                int tp2 = t - 1;
                if (tp2 >= 0)
                    llc_load16(h2[i], hist + (((size_t)2 * RSLOTS + (tp2 & 63)) * 128 + n) * 256 + ko);
            }
        }

        // ---- (M1) char-part MFMA (k in [0,256)) — hides h-load latency
        f32x4 acc0 = {0.f,0.f,0.f,0.f}, acc1 = {0.f,0.f,0.f,0.f}, acc2 = {0.f,0.f,0.f,0.f};
        #pragma unroll
        for (int ks = 0; ks < 8; ks++) {
            bf16x8 a  = *(const bf16x8*)(ap + ks * 512);
            bf16x8 b0 = *(const bf16x8*)(bp0 + ks * 32);
            bf16x8 b1 = *(const bf16x8*)(bp1 + ks * 32);
            bf16x8 b2 = *(const bf16x8*)(bp2 + ks * 32);
            acc0 = __builtin_amdgcn_mfma_f32_16x16x32_bf16(a, b0, acc0, 0, 0, 0);
            acc1 = __builtin_amdgcn_mfma_f32_16x16x32_bf16(a, b1, acc1, 0, 0, 0);
            acc2 = __builtin_amdgcn_mfma_f32_16x16x32_bf16(a, b2, acc2, 0, 0, 0);
        }

        // ---- single wait for all h loads, then stage into Alds
        drain_vmem();
        __builtin_amdgcn_sched_barrier(0);
        {
            #pragma unroll
            for (int i = 0; i < 4; i++) {
                int q = tid + 128 * i; int r = q >> 5; int ko = (q & 31) << 3;
                int kg = 256 + ko;
                int pos = (kg >> 5) * 512 + (r + 16 * ((ko >> 3) & 3)) * 8;
                int tp0 = (0 == s) ? (t - 1) : t;
                if (tp0 >= 0) *(uint4*)(Alds + pos) = h0[i];
                else { uint4 z = {0,0,0,0}; *(uint4*)(Alds + pos) = z; }
            }
            if (s >= 1) {
                #pragma unroll
                for (int i = 0; i < 4; i++) {
                    int q = tid + 128 * i; int r = q >> 5; int ko = (q & 31) << 3;
                    int kg = 512 + ko;
                    int pos = (kg >> 5) * 512 + (r + 16 * ((ko >> 3) & 3)) * 8;
                    int tp1 = (1 == s) ? (t - 1) : t;
                    if (tp1 >= 0) *(uint4*)(Alds + pos) = h1[i];
                    else { uint4 z = {0,0,0,0}; *(uint4*)(Alds + pos) = z; }
                }
            }
            if (s == 2) {
                #pragma unroll
                for (int i = 0; i < 4; i++) {
                    int q = tid + 128 * i; int r = q >> 5; int ko = (q & 31) << 3;
                    int kg = 768 + ko;
                    int pos = (kg >> 5) * 512 + (r + 16 * ((ko >> 3) & 3)) * 8;
                    if (t >= 1) *(uint4*)(Alds + pos) = h2[i];
                    else { uint4 z = {0,0,0,0}; *(uint4*)(Alds + pos) = z; }
                }
            }
        }
        __syncthreads();   // B2: h staged

        // ---- consumption acks (fire-and-forget, off critical path)
        if (tid == 0) {
            if (t > 0)  __hip_atomic_fetch_add(&cons[((s * 512) + (t - 1)) * 8 + g], 1, __ATOMIC_RELAXED, __HIP_MEMORY_SCOPE_AGENT);
            if (s >= 1) __hip_atomic_fetch_add(&cons[t * 8 + g], 1, __ATOMIC_RELAXED, __HIP_MEMORY_SCOPE_AGENT);
            if (s == 2) __hip_atomic_fetch_add(&cons[(512 + t) * 8 + g], 1, __ATOMIC_RELAXED, __HIP_MEMORY_SCOPE_AGENT);
        }

        // ---- (M2) h-part MFMA (k in [256, Ks))
        #pragma unroll
        for (int p = 0; p < 3; p++) {
            if (p > s) continue;
            #pragma unroll
            for (int j = 0; j < 8; j++) {
                int ks = 8 + 8 * p + j;
                bf16x8 a  = *(const bf16x8*)(ap + ks * 512);
                bf16x8 b0 = *(const bf16x8*)(bp0 + ks * 32);
                bf16x8 b1 = *(const bf16x8*)(bp1 + ks * 32);
                bf16x8 b2 = *(const bf16x8*)(bp2 + ks * 32);
                acc0 = __builtin_amdgcn_mfma_f32_16x16x32_bf16(a, b0, acc0, 0, 0, 0);
                acc1 = __builtin_amdgcn_mfma_f32_16x16x32_bf16(a, b1, acc1, 0, 0, 0);
                acc2 = __builtin_amdgcn_mfma_f32_16x16x32_bf16(a, b2, acc2, 0, 0, 0);
            }
        }
        {
            int rbase = (lane >> 4) * 4;
            int c0 = w * 48 + (lane & 15);
            #pragma unroll
            for (int q = 0; q < 4; q++) {
                glds[(rbase + q) * GL + c0]      = acc0[q];
                glds[(rbase + q) * GL + c0 + 16] = acc1[q];
                glds[(rbase + q) * GL + c0 + 32] = acc2[q];
            }
        }
        __syncthreads();   // B3: gates ready

        // ---- gating + h publish (critical path), head projection deferred past flag
        int sl = tid >> 3;
        int d0 = (tid & 7) * 4;
        int n  = g * 16 + sl;
        float hv[4];
        {
            const float* gcp = gc + (size_t)(s * 128 + n) * 768 + b * 96;
            union { ushort u[4]; ull v; } hpk;
            #pragma unroll
            for (int dd = 0; dd < 4; dd++) {
                int d32 = d0 + dd;
                int d   = b * 32 + d32;
                float rp = glds[sl * GL + d32]      + gcp[d32];
                float zp = glds[sl * GL + 32 + d32] + gcp[32 + d32];
                float np = glds[sl * GL + 64 + d32] + gcp[64 + d32];
                float rg = sigmoidf_(rp);
                float zg = sigmoidf_(zp);
                float ng = tanhf(np + rg * bhh[512 + d]);
                float h  = (1.0f - zg) * ng;
                hv[dd] = h;
                hpk.u[dd] = f2bf(h);
            }
            llc_store8(hist + (((size_t)s * RSLOTS + (t & 63)) * 128 + n) * 256 + b * 32 + d0, hpk.v);
        }
        // EVERY WAVE drains its own write-through h stores to the LLC before the
        // barrier (vmcnt is per-wave; the compiler does not emit this for inline-asm
        // stores). After B4, all h data is at the coherence point -> relaxed flag OK.
        drain_vmem();
        __syncthreads();   // B4
        if (tid == 0) {
            __hip_atomic_fetch_add(&flag[((s * 512) + t) * 8 + g], 1, __ATOMIC_RELAXED, __HIP_MEMORY_SCOPE_AGENT);
        }
        // ---- head projection + output (off the recurrence critical path)
        {
            float y0 = 0.f, y1 = 0.f;
            #pragma unroll
            for (int dd = 0; dd < 4; dd++) {
                int d = b * 32 + d0 + dd;
                y0 += hv[dd] * hw[d];
                y1 += hv[dd] * hw[256 + d];
            }
            y0 += __shfl_xor(y0, 1); y0 += __shfl_xor(y0, 2); y0 += __shfl_xor(y0, 4);
            y1 += __shfl_xor(y1, 1); y1 += __shfl_xor(y1, 2); y1 += __shfl_xor(y1, 4);
            if ((tid & 7) == 0) {
                if (b == 0) { y0 += hb[0]; y1 += hb[1]; }
                int bb = n >> 3, cc = n & 7;
                atomicAdd(out + (size_t)s * 131072 + (size_t)((bb * 2 + 0) * 8 + cc) * 512 + t, y0);
                atomicAdd(out + (size_t)s * 131072 + (size_t)((bb * 2 + 1) * 8 + cc) * 512 + t, y1);
            }
        }
    }
}

// ---------------- legacy pipelined step kernel (fallback when ws is small)
__global__ void __launch_bounds__(128) k_step(
    const float* __restrict__ chars, const ushort* __restrict__ wt,
    const float* __restrict__ gc, ushort* __restrict__ ring,
    const float* __restrict__ bhh0, const float* __restrict__ bhh1, const float* __restrict__ bhh2,
    const float* __restrict__ hw0, const float* __restrict__ hw1, const float* __restrict__ hw2,
    const float* __restrict__ hb0, const float* __restrict__ hb1, const float* __restrict__ hb2,
    float* __restrict__ out, int stepi) {
    __shared__ ushort Alds[16384];
    __shared__ float  glds[16 * GL];

    int bx = blockIdx.x;
    int s  = bx >> 6;
    int r2 = bx & 63;
    int mt = r2 >> 3;
    int nb = r2 & 7;
    int t  = stepi - s;
    if (t < 0 || t >= T_STEPS) return;

    int Ks = 512 + 256 * s;
    const ushort* wts = wt + ((s == 0) ? 0 : ((s == 1) ? 393216 : 983040));
    int tid = threadIdx.x;

    #pragma unroll
    for (int i = 0; i < 4; i++) {
        int q  = tid + 128 * i;
        int r  = q >> 5;
        int ko = (q & 31) << 3;
        int n  = mt * 16 + r;
        const float* src = chars + ((size_t)n * T_STEPS + t) * 256 + ko;
        float4 f0 = *(const float4*)src;
        float4 f1 = *(const float4*)(src + 4);
        union { ushort u[8]; uint4 v; } pk;
        pk.u[0] = f2bf(f0.x); pk.u[1] = f2bf(f0.y); pk.u[2] = f2bf(f0.z); pk.u[3] = f2bf(f0.w);
        pk.u[4] = f2bf(f1.x); pk.u[5] = f2bf(f1.y); pk.u[6] = f2bf(f1.z); pk.u[7] = f2bf(f1.w);
        int pos = (ko >> 5) * 512 + (r + 16 * ((ko >> 3) & 3)) * 8;
        *(uint4*)(Alds + pos) = pk.v;
    }
    int nparts = s + 1;
    for (int p = 0; p < nparts; p++) {
        int slot = (p == s) ? ((t - 1) & 3) : (t & 3);
        const ushort* hsrc = ring + ((size_t)p * 4 + slot) * (128 * 256);
        #pragma unroll
        for (int i = 0; i < 4; i++) {
            int q  = tid + 128 * i;
            int r  = q >> 5;
            int ko = (q & 31) << 3;
            int n  = mt * 16 + r;
            uint4 v = *(const uint4*)(hsrc + (size_t)n * 256 + ko);
            int kg  = 256 + p * 256 + ko;
            int pos = (kg >> 5) * 512 + (r + 16 * ((kg >> 3) & 3)) * 8;
            *(uint4*)(Alds + pos) = v;
        }
    }
    __syncthreads();

    int w = tid >> 6, lane = tid & 63;
    int cbcol = nb * 96 + w * 48;
    f32x4 acc0 = {0.f,0.f,0.f,0.f}, acc1 = {0.f,0.f,0.f,0.f}, acc2 = {0.f,0.f,0.f,0.f};
    const ushort* bp0 = wts + (size_t)(cbcol + (lane & 15)) * Ks + ((lane >> 4) << 3);
    const ushort* bp1 = bp0 + 16 * (size_t)Ks;
    const ushort* bp2 = bp0 + 32 * (size_t)Ks;
    const ushort* ap  = Alds + lane * 8;
    int nk = Ks >> 5;
    #pragma unroll 8
    for (int ks = 0; ks < nk; ks++) {
        bf16x8 a  = *(const bf16x8*)(ap + ks * 512);
        bf16x8 b0 = *(const bf16x8*)(bp0 + ks * 32);
        bf16x8 b1 = *(const bf16x8*)(bp1 + ks * 32);
        bf16x8 b2 = *(const bf16x8*)(bp2 + ks * 32);
        acc0 = __builtin_amdgcn_mfma_f32_16x16x32_bf16(a, b0, acc0, 0, 0, 0);
        acc1 = __builtin_amdgcn_mfma_f32_16x16x32_bf16(a, b1, acc1, 0, 0, 0);
        acc2 = __builtin_amdgcn_mfma_f32_16x16x32_bf16(a, b2, acc2, 0, 0, 0);
    }
    {
        int rbase = (lane >> 4) * 4;
        int c0 = w * 48 + (lane & 15);
        #pragma unroll
        for (int q = 0; q < 4; q++) {
            glds[(rbase + q) * GL + c0]      = acc0[q];
            glds[(rbase + q) * GL + c0 + 16] = acc1[q];
            glds[(rbase + q) * GL + c0 + 32] = acc2[q];
        }
    }
    __syncthreads();

    {
        int sl = tid >> 3;
        int d0 = (tid & 7) * 4;
        int n  = mt * 16 + sl;
        const float* bhh = (s == 0) ? bhh0 : ((s == 1) ? bhh1 : bhh2);
        const float* hw  = (s == 0) ? hw0  : ((s == 1) ? hw1  : hw2);
        const float* hb  = (s == 0) ? hb0  : ((s == 1) ? hb1  : hb2);
        const float* gcp = gc + (size_t)(s * 128 + n) * 768 + nb * 96;
        float y0 = 0.f, y1 = 0.f;
        union { ushort u[4]; uint2 v; } hpk;
        #pragma unroll
        for (int dd = 0; dd < 4; dd++) {
            int d32 = d0 + dd;
            int d   = nb * 32 + d32;
            float rp = glds[sl * GL + d32]      + gcp[d32];
            float zp = glds[sl * GL + 32 + d32] + gcp[32 + d32];
            float np = glds[sl * GL + 64 + d32] + gcp[64 + d32];
            float rg = sigmoidf_(rp);
            float zg = sigmoidf_(zp);
            float ng = tanhf(np + rg * bhh[512 + d]);
            float h  = (1.0f - zg) * ng;
            hpk.u[dd] = f2bf(h);
            y0 += h * hw[d];
            y1 += h * hw[256 + d];
        }
        *(uint2*)(ring + (((size_t)s * 4 + (t & 3)) * 128 + n) * 256 + nb * 32 + d0) = hpk.v;
        y0 += __shfl_xor(y0, 1); y0 += __shfl_xor(y0, 2); y0 += __shfl_xor(y0, 4);
        y1 += __shfl_xor(y1, 1); y1 += __shfl_xor(y1, 2); y1 += __shfl_xor(y1, 4);
        if ((tid & 7) == 0) {
            if (nb == 0) { y0 += hb[0]; y1 += hb[1]; }
            int bb = n >> 3, cc = n & 7;
            atomicAdd(out + (size_t)s * 131072 + (size_t)((bb * 2 + 0) * 8 + cc) * 512 + t, y0);
            atomicAdd(out + (size_t)s * 131072 + (size_t)((bb * 2 + 1) * 8 + cc) * 512 + t, y1);
        }
    }
}

extern "C" void kernel_launch(void* const* d_in, const int* in_sizes, int n_in,
                              void* d_out, int out_size, void* d_ws, size_t ws_size,
                              hipStream_t stream) {
    const float* chars = (const float*)d_in[0];
    const float* sent  = (const float*)d_in[1];
    const float* ctx   = (const float*)d_in[2];
    const float* w0    = (const float*)d_in[3];
    const float* bih0  = (const float*)d_in[4];
    const float* bhh0  = (const float*)d_in[5];
    const float* w1    = (const float*)d_in[6];
    const float* bih1  = (const float*)d_in[7];
    const float* bhh1  = (const float*)d_in[8];
    const float* w2    = (const float*)d_in[9];
    const float* bih2  = (const float*)d_in[10];
    const float* bhh2  = (const float*)d_in[11];
    const float* hw0   = (const float*)d_in[12];
    const float* hb0   = (const float*)d_in[13];
    const float* hw1   = (const float*)d_in[14];
    const float* hb1   = (const float*)d_in[15];
    const float* hw2   = (const float*)d_in[16];
    const float* hb2   = (const float*)d_in[17];

    char* ws = (char*)d_ws;
    ushort* wt   = (ushort*)(ws + WT_OFF);
    float*  gcb  = (float*)(ws + GC_OFF);
    float*  out  = (float*)d_out;

    hipMemsetAsync(d_out, 0, (size_t)out_size * sizeof(float), stream);
    k_prep<<<6912, 256, 0, stream>>>(w0, w1, w2, wt);
    k_gconst<<<1152, 256, 0, stream>>>(w0, w1, w2, bih0, bih1, bih2,
                                       bhh0, bhh1, bhh2, sent, ctx, gcb);

    if (ws_size >= NEED_MID) {
        int*    flag = (int*)(ws + FLAG_OFF);
        int*    cons = (int*)(ws + CONS_OFF);
        ushort* hist = (ushort*)(ws + HIST_OFF);
        ushort* cbuf = (ushort*)(ws + CB_OFF);
        int use_cb = (ws_size >= NEED_FULL) ? 1 : 0;
        hipMemsetAsync(ws + FLAG_OFF, 0, 98304, stream);   // flag + cons
        if (use_cb) k_cprep<<<8192, 256, 0, stream>>>(chars, cbuf);
        k_run<<<192, 128, 0, stream>>>(chars, use_cb ? cbuf : (const ushort*)nullptr, use_cb,
                                       wt, gcb, hist, flag, cons,
                                       bhh0, bhh1, bhh2, hw0, hw1, hw2,
                                       hb0, hb1, hb2, out);
    } else {
        ushort* ring = (ushort*)(ws + RING_OFF);
        hipMemsetAsync(ring, 0, (size_t)3 * 4 * 128 * 256 * 2, stream);
        for (int i = 0; i < T_STEPS + 2; i++) {
            k_step<<<192, 128, 0, stream>>>(chars, wt, gcb, ring,
                                            bhh0, bhh1, bhh2, hw0, hw1, hw2,
                                            hb0, hb1, hb2, out, i);
        }
    }
}